// Round 4
// baseline (625.906 us; speedup 1.0000x reference)
//
#include <hip/hip_runtime.h>
#include <cstdint>
#include <cstddef>

#define N_NODES 2048
#define N_EDGES 32768
#define ROW_CAP 384   // max row degree ~222 (mean 164, sd 12.8)
#define COL_CAP 48    // max col degree ~26  (mean 10.2, sd 3.2)

typedef unsigned short u16;
typedef __bf16 bf16x8 __attribute__((ext_vector_type(8)));
typedef float f32x4 __attribute__((ext_vector_type(4)));
typedef uint32_t u32x4 __attribute__((ext_vector_type(4)));

union BF8 {
  bf16x8 v;
  u16 s[8];
  uint4 q;
};

__device__ __forceinline__ u16 f2bf(float f) {
  uint32_t u = __float_as_uint(f);
  uint32_t r = (u + 0x7fffu + ((u >> 16) & 1u)) >> 16;  // RNE
  return (u16)r;
}
__device__ __forceinline__ float bf2f(u16 h) {
  return __uint_as_float(((uint32_t)h) << 16);
}
__device__ __forceinline__ float logsig(float x) {
  return fminf(x, 0.0f) - __logf(1.0f + __expf(-fabsf(x)));
}

// ---------------------------------------------------------------------------
// K1: weights fp32->bf16 + zero col_cnt.
// wb layout (elements): [0,16384)=W1m, [16384,32768)=W2m,
//                       [32768,53248)=W1a(128x160), [53248,69632)=W2a
// ---------------------------------------------------------------------------
__global__ __launch_bounds__(256) void conv_weights(
    const float* __restrict__ W1m, const float* __restrict__ W2m,
    const float* __restrict__ W1a, const float* __restrict__ W2a,
    u16* __restrict__ wb, int* __restrict__ col_cnt)
{
  const int i = blockIdx.x * 256 + threadIdx.x;
  if (i < N_EDGES) col_cnt[i] = 0;
  if (i < 16384)      wb[i] = f2bf(W1m[i]);
  else if (i < 32768) wb[i] = f2bf(W2m[i - 16384]);
  else if (i < 53248) wb[i] = f2bf(W1a[i - 32768]);
  else if (i < 69632) wb[i] = f2bf(W2a[i - 53248]);
}

// ---------------------------------------------------------------------------
// K2: fused. Blocks [0,256): MLP_m  s = ls(ls(state@W1m^T+b1m)@W2m^T) -> bf16.
//           Blocks [256,2304): scan mask row n = blockIdx-256, ballot-compact
//           nonzero edges -> row_edges CSR + atomic scatter -> col lists.
// The HBM-bound mask stream (~42 us floor) hides the MLP compute.
// mask_transpose is never read (== mask.T). Mask loads nontemporal: 268 MB
// of single-use stream must not evict s/y from L2. Wave-uniform early-out
// skips the 4-ballot path for the ~27% of wave-iters whose 1KB is all-zero.
// ---------------------------------------------------------------------------
__global__ __launch_bounds__(256) void mlp_scan(
    const float* __restrict__ state, const u16* __restrict__ W1b,
    const float* __restrict__ b1, const u16* __restrict__ W2b,
    u16* __restrict__ s_out,
    const float* __restrict__ mask, int* __restrict__ row_cnt,
    int* __restrict__ row_edges, int* __restrict__ col_cnt,
    int* __restrict__ col_nodes)
{
  const int tid = threadIdx.x;

  __shared__ u16 h_lds[128][136];
  __shared__ int cnt;
  __shared__ int list[ROW_CAP];

  if (blockIdx.x < 256) {
    // ---------------- MLP_m ----------------
    const int wave = tid >> 6;
    const int lane = tid & 63;
    const int l16 = lane & 15;
    const int quad = lane >> 4;
    const int row0 = blockIdx.x * 128;

    const f32x4 vzero = {0.f, 0.f, 0.f, 0.f};
    f32x4 acc[2][8];
    for (int rt = 0; rt < 2; ++rt)
      for (int ct = 0; ct < 8; ++ct) acc[rt][ct] = vzero;

    for (int kc = 0; kc < 4; ++kc) {
      const int k0 = kc * 32 + quad * 8;
      BF8 a[2];
      for (int rt = 0; rt < 2; ++rt) {
        const float* ap = state + (size_t)(row0 + wave * 32 + rt * 16 + l16) * 128 + k0;
        const float4 f0 = ((const float4*)ap)[0];
        const float4 f1 = ((const float4*)ap)[1];
        a[rt].s[0] = f2bf(f0.x); a[rt].s[1] = f2bf(f0.y);
        a[rt].s[2] = f2bf(f0.z); a[rt].s[3] = f2bf(f0.w);
        a[rt].s[4] = f2bf(f1.x); a[rt].s[5] = f2bf(f1.y);
        a[rt].s[6] = f2bf(f1.z); a[rt].s[7] = f2bf(f1.w);
      }
      for (int ct = 0; ct < 8; ++ct) {
        BF8 b;
        b.q = *(const uint4*)(W1b + (size_t)(ct * 16 + l16) * 128 + k0);
        for (int rt = 0; rt < 2; ++rt)
          acc[rt][ct] = __builtin_amdgcn_mfma_f32_16x16x32_bf16(a[rt].v, b.v, acc[rt][ct], 0, 0, 0);
      }
    }

    for (int ct = 0; ct < 8; ++ct) {
      const int col = ct * 16 + l16;
      const float bias = b1[col];
      for (int rt = 0; rt < 2; ++rt) {
        const int r = wave * 32 + rt * 16 + quad * 4;
        for (int i = 0; i < 4; ++i)
          h_lds[r + i][col] = f2bf(logsig(acc[rt][ct][i] + bias));
      }
    }
    __syncthreads();

    f32x4 acc2[2][8];
    for (int rt = 0; rt < 2; ++rt)
      for (int ct = 0; ct < 8; ++ct) acc2[rt][ct] = vzero;

    for (int kc = 0; kc < 4; ++kc) {
      const int k0 = kc * 32 + quad * 8;
      BF8 a[2];
      for (int rt = 0; rt < 2; ++rt)
        a[rt].q = *(const uint4*)&h_lds[wave * 32 + rt * 16 + l16][k0];
      for (int ct = 0; ct < 8; ++ct) {
        BF8 b;
        b.q = *(const uint4*)(W2b + (size_t)(ct * 16 + l16) * 128 + k0);
        for (int rt = 0; rt < 2; ++rt)
          acc2[rt][ct] = __builtin_amdgcn_mfma_f32_16x16x32_bf16(a[rt].v, b.v, acc2[rt][ct], 0, 0, 0);
      }
    }

    for (int ct = 0; ct < 8; ++ct) {
      const int col = ct * 16 + l16;
      for (int rt = 0; rt < 2; ++rt) {
        const int r = row0 + wave * 32 + rt * 16 + quad * 4;
        for (int i = 0; i < 4; ++i)
          s_out[(size_t)(r + i) * 128 + col] = f2bf(logsig(acc2[rt][ct][i]));
      }
    }
  } else {
    // ---------------- mask scan ----------------
    const int n = blockIdx.x - 256;
    const int lane = tid & 63;
    if (tid == 0) cnt = 0;
    __syncthreads();

    const u32x4* row = (const u32x4*)(mask + (size_t)n * N_EDGES);
    for (int i = tid; i < N_EDGES / 4; i += 256) {
      const u32x4 v = __builtin_nontemporal_load(&row[i]);
      const uint32_t any = v[0] | v[1] | v[2] | v[3];
      const unsigned long long many = __ballot(any != 0u);
      if (many) {
#pragma unroll
        for (int k = 0; k < 4; ++k) {
          const bool p = (v[k] != 0u);
          const unsigned long long m = __ballot(p);
          if (m) {
            int base = 0;
            if (lane == 0) base = atomicAdd(&cnt, __popcll(m));
            base = __shfl(base, 0);
            if (p) {
              const int off = __popcll(m & ((1ull << lane) - 1ull));
              if (base + off < ROW_CAP) list[base + off] = i * 4 + k;
            }
          }
        }
      }
    }
    __syncthreads();

    const int c = min(cnt, ROW_CAP);
    if (tid == 0) row_cnt[n] = c;
    for (int i = tid; i < c; i += 256) {
      const int e = list[i];
      row_edges[(size_t)n * ROW_CAP + i] = e;
      const int slot = atomicAdd(&col_cnt[e], 1);
      if (slot < COL_CAP) col_nodes[(size_t)e * COL_CAP + slot] = n;
    }
  }
}

// ---------------------------------------------------------------------------
// K3: y[n,:] = sum_{e in row n} s[e,:]   (mask @ s). One block per node,
// 256 threads = 4 waves; each wave covers all 128 dims (2 dims/lane, u32
// loads) over strided edges; 4 partials combined through LDS.
// ---------------------------------------------------------------------------
__global__ __launch_bounds__(256) void pass_a(
    const u16* __restrict__ s_bf, const int* __restrict__ row_cnt,
    const int* __restrict__ row_edges, float* __restrict__ y)
{
  const int n = blockIdx.x;
  const int lane = threadIdx.x & 63;
  const int wv = threadIdx.x >> 6;
  const int d0 = lane * 2;
  __shared__ int elist[ROW_CAP];
  __shared__ float part[3][128];
  const int cnt = row_cnt[n];
  for (int i = threadIdx.x; i < cnt; i += 256)
    elist[i] = row_edges[(size_t)n * ROW_CAP + i];
  __syncthreads();
  float a0 = 0.f, a1 = 0.f;
#pragma unroll 4
  for (int i = wv; i < cnt; i += 4) {
    const uint32_t sp = *(const uint32_t*)&s_bf[(size_t)elist[i] * 128 + d0];
    a0 += bf2f((u16)(sp & 0xffffu));
    a1 += bf2f((u16)(sp >> 16));
  }
  if (wv > 0) { part[wv - 1][d0] = a0; part[wv - 1][d0 + 1] = a1; }
  __syncthreads();
  if (wv == 0) {
    a0 += part[0][d0] + part[1][d0] + part[2][d0];
    a1 += part[0][d0 + 1] + part[1][d0 + 1] + part[2][d0 + 1];
    float2 r; r.x = a0; r.y = a1;
    *(float2*)&y[n * 128 + d0] = r;
  }
}

// ---------------------------------------------------------------------------
// K4: fused pass_b + MLP_a. 64 edges/block, 512 blocks, 39 KB LDS
// (up to 4 blocks/CU — round 2's 78 KB/1-block failure mode avoided).
// Phase 1: cat[le,:] = [ (sum_{n in col e} y[n,:]) - s[e,:] | feature[e,:] ],
//          one edge per wave per step (16 steps); column list preloaded
//          one-entry-per-lane and broadcast via __shfl -> y-loads independent.
// Phase 2: out = ls(ls(cat @ W1a^T + b1a) @ W2a^T), K1=160, f32 out.
// ---------------------------------------------------------------------------
__global__ __launch_bounds__(256) void agg_mlp(
    const float* __restrict__ y, const u16* __restrict__ s_bf,
    const float* __restrict__ feature, const int* __restrict__ col_cnt,
    const int* __restrict__ col_nodes,
    const u16* __restrict__ W1b, const float* __restrict__ b1,
    const u16* __restrict__ W2b, float* __restrict__ out)
{
  const int tid = threadIdx.x;
  const int wave = tid >> 6;
  const int lane = tid & 63;
  const int row0 = blockIdx.x * 64;

  __shared__ u16 cat[64][168];    // 160 data + 8 pad (row stride 336 B, 16B-mult)
  __shared__ u16 h_lds[64][136];

  // ---- phase 1: build cat rows, one edge per wave per step ----
  const int d0 = lane * 2;
  for (int it = 0; it < 16; ++it) {
    const int le = it * 4 + wave;
    const int e = row0 + le;
    const int cnt = min(col_cnt[e], COL_CAP);
    const int cnl = col_nodes[(size_t)e * COL_CAP + min(lane, COL_CAP - 1)];
    float a0 = 0.f, a1 = 0.f;
#pragma unroll 4
    for (int j = 0; j < cnt; ++j) {
      const int nn = __shfl(cnl, j);
      const float2 yv = *(const float2*)&y[nn * 128 + d0];
      a0 += yv.x; a1 += yv.y;
    }
    const uint32_t sp = *(const uint32_t*)&s_bf[(size_t)e * 128 + d0];
    a0 -= bf2f((u16)(sp & 0xffffu));
    a1 -= bf2f((u16)(sp >> 16));
    const uint32_t packed = (uint32_t)f2bf(a0) | ((uint32_t)f2bf(a1) << 16);
    *(uint32_t*)&cat[le][d0] = packed;
    if (lane < 16) {
      const float2 fv = *(const float2*)&feature[e * 32 + lane * 2];
      const uint32_t pf = (uint32_t)f2bf(fv.x) | ((uint32_t)f2bf(fv.y) << 16);
      *(uint32_t*)&cat[le][128 + lane * 2] = pf;
    }
  }
  __syncthreads();

  // ---- phase 2: 2-layer MLP; wave handles 16 rows (rows wave*16..+15) ----
  const int l16 = lane & 15;
  const int quad = lane >> 4;
  const f32x4 vzero = {0.f, 0.f, 0.f, 0.f};
  f32x4 acc[8];
  for (int ct = 0; ct < 8; ++ct) acc[ct] = vzero;

  for (int kc = 0; kc < 5; ++kc) {
    const int k0 = kc * 32 + quad * 8;
    BF8 a;
    a.q = *(const uint4*)&cat[wave * 16 + l16][k0];
    for (int ct = 0; ct < 8; ++ct) {
      BF8 b;
      b.q = *(const uint4*)(W1b + (size_t)(ct * 16 + l16) * 160 + k0);
      acc[ct] = __builtin_amdgcn_mfma_f32_16x16x32_bf16(a.v, b.v, acc[ct], 0, 0, 0);
    }
  }

  for (int ct = 0; ct < 8; ++ct) {
    const int col = ct * 16 + l16;
    const float bias = b1[col];
    const int r = wave * 16 + quad * 4;
    for (int i = 0; i < 4; ++i)
      h_lds[r + i][col] = f2bf(logsig(acc[ct][i] + bias));
  }
  __syncthreads();

  f32x4 acc2[8];
  for (int ct = 0; ct < 8; ++ct) acc2[ct] = vzero;

  for (int kc = 0; kc < 4; ++kc) {
    const int k0 = kc * 32 + quad * 8;
    BF8 a;
    a.q = *(const uint4*)&h_lds[wave * 16 + l16][k0];
    for (int ct = 0; ct < 8; ++ct) {
      BF8 b;
      b.q = *(const uint4*)(W2b + (size_t)(ct * 16 + l16) * 128 + k0);
      acc2[ct] = __builtin_amdgcn_mfma_f32_16x16x32_bf16(a.v, b.v, acc2[ct], 0, 0, 0);
    }
  }

  for (int ct = 0; ct < 8; ++ct) {
    const int col = ct * 16 + l16;
    const int r = row0 + wave * 16 + quad * 4;
    for (int i = 0; i < 4; ++i)
      out[(size_t)(r + i) * 128 + col] = logsig(acc2[ct][i]);
  }
}

// ---------------------------------------------------------------------------
// kernel_launch
// ---------------------------------------------------------------------------
extern "C" void kernel_launch(void* const* d_in, const int* in_sizes, int n_in,
                              void* d_out, int out_size, void* d_ws, size_t ws_size,
                              hipStream_t stream)
{
  const float* state   = (const float*)d_in[0];
  const float* feature = (const float*)d_in[1];
  const float* mask    = (const float*)d_in[2];
  // d_in[3] = mask_transpose — intentionally unused (== mask.T)
  const float* W1m = (const float*)d_in[4];
  const float* b1m = (const float*)d_in[5];
  const float* W2m = (const float*)d_in[6];
  const float* W1a = (const float*)d_in[7];
  const float* b1a = (const float*)d_in[8];
  const float* W2a = (const float*)d_in[9];
  float* out = (float*)d_out;

  char* ws = (char*)d_ws;
  u16*  s_bf      = (u16*)(ws);                 //  8,388,608 B  [E,128] bf16
  float* y        = (float*)(ws + 8388608);     //  1,048,576 B  [N,128] f32
  int*  row_cnt   = (int*)(ws + 9437184);       //      8,192 B
  int*  row_edges = (int*)(ws + 9445376);       //  3,145,728 B
  int*  col_cnt   = (int*)(ws + 12591104);      //    131,072 B
  int*  col_nodes = (int*)(ws + 12722176);      //  6,291,456 B
  u16*  wb        = (u16*)(ws + 19013632);      //    139,264 B  bf16 weights

  conv_weights<<<272, 256, 0, stream>>>(W1m, W2m, W1a, W2a, wb, col_cnt);
  mlp_scan<<<256 + N_NODES, 256, 0, stream>>>(state, wb, b1m, wb + 16384, s_bf,
                                              mask, row_cnt, row_edges, col_cnt, col_nodes);
  pass_a<<<N_NODES, 256, 0, stream>>>(s_bf, row_cnt, row_edges, y);
  agg_mlp<<<N_EDGES / 64, 256, 0, stream>>>(y, s_bf, feature, col_cnt, col_nodes,
                                            wb + 32768, b1a, wb + 53248, out);
}

// Round 5
// 589.037 us; speedup vs baseline: 1.0626x; 1.0626x over previous
//
#include <hip/hip_runtime.h>
#include <cstdint>
#include <cstddef>

#define N_NODES 2048
#define N_EDGES 32768
#define ROW_CAP 384   // max row degree ~222 (mean 164, sd 12.8)
#define COL_CAP 48    // max col degree ~26  (mean 10.2, sd 3.2)

typedef unsigned short u16;
typedef __bf16 bf16x8 __attribute__((ext_vector_type(8)));
typedef float f32x4 __attribute__((ext_vector_type(4)));
typedef uint32_t u32x4 __attribute__((ext_vector_type(4)));

union BF8 {
  bf16x8 v;
  u16 s[8];
  uint4 q;
};

__device__ __forceinline__ u16 f2bf(float f) {
  uint32_t u = __float_as_uint(f);
  uint32_t r = (u + 0x7fffu + ((u >> 16) & 1u)) >> 16;  // RNE
  return (u16)r;
}
__device__ __forceinline__ float bf2f(u16 h) {
  return __uint_as_float(((uint32_t)h) << 16);
}
__device__ __forceinline__ float logsig(float x) {
  return fminf(x, 0.0f) - __logf(1.0f + __expf(-fabsf(x)));
}

// ---------------------------------------------------------------------------
// K1: weights fp32->bf16 + zero col_cnt.
// wb layout (elements): [0,16384)=W1m, [16384,32768)=W2m,
//                       [32768,53248)=W1a(128x160), [53248,69632)=W2a
// ---------------------------------------------------------------------------
__global__ __launch_bounds__(256) void conv_weights(
    const float* __restrict__ W1m, const float* __restrict__ W2m,
    const float* __restrict__ W1a, const float* __restrict__ W2a,
    u16* __restrict__ wb, int* __restrict__ col_cnt)
{
  const int i = blockIdx.x * 256 + threadIdx.x;
  if (i < N_EDGES) col_cnt[i] = 0;
  if (i < 16384)      wb[i] = f2bf(W1m[i]);
  else if (i < 32768) wb[i] = f2bf(W2m[i - 16384]);
  else if (i < 53248) wb[i] = f2bf(W1a[i - 32768]);
  else if (i < 69632) wb[i] = f2bf(W2a[i - 53248]);
}

// ---------------------------------------------------------------------------
// K2: fused. Blocks [0,256): MLP_m  s = ls(ls(state@W1m^T+b1m)@W2m^T) -> bf16.
//           Blocks [256,2304): scan mask row n = blockIdx-256, ballot-compact
//           nonzero edges -> row_edges CSR + atomic scatter -> col lists.
// The HBM-bound mask stream (~42 us floor) hides the MLP compute.
// mask_transpose is never read (== mask.T). Mask loads nontemporal: 268 MB
// of single-use stream must not evict s/y from L2. Wave-uniform early-out
// skips the 4-ballot path for the ~27% of wave-iters whose 1KB is all-zero.
// ---------------------------------------------------------------------------
__global__ __launch_bounds__(256) void mlp_scan(
    const float* __restrict__ state, const u16* __restrict__ W1b,
    const float* __restrict__ b1, const u16* __restrict__ W2b,
    u16* __restrict__ s_out,
    const float* __restrict__ mask, int* __restrict__ row_cnt,
    int* __restrict__ row_edges, int* __restrict__ col_cnt,
    int* __restrict__ col_nodes)
{
  const int tid = threadIdx.x;

  __shared__ u16 h_lds[128][136];
  __shared__ int cnt;
  __shared__ int list[ROW_CAP];

  if (blockIdx.x < 256) {
    // ---------------- MLP_m ----------------
    const int wave = tid >> 6;
    const int lane = tid & 63;
    const int l16 = lane & 15;
    const int quad = lane >> 4;
    const int row0 = blockIdx.x * 128;

    const f32x4 vzero = {0.f, 0.f, 0.f, 0.f};
    f32x4 acc[2][8];
    for (int rt = 0; rt < 2; ++rt)
      for (int ct = 0; ct < 8; ++ct) acc[rt][ct] = vzero;

    for (int kc = 0; kc < 4; ++kc) {
      const int k0 = kc * 32 + quad * 8;
      BF8 a[2];
      for (int rt = 0; rt < 2; ++rt) {
        const float* ap = state + (size_t)(row0 + wave * 32 + rt * 16 + l16) * 128 + k0;
        const float4 f0 = ((const float4*)ap)[0];
        const float4 f1 = ((const float4*)ap)[1];
        a[rt].s[0] = f2bf(f0.x); a[rt].s[1] = f2bf(f0.y);
        a[rt].s[2] = f2bf(f0.z); a[rt].s[3] = f2bf(f0.w);
        a[rt].s[4] = f2bf(f1.x); a[rt].s[5] = f2bf(f1.y);
        a[rt].s[6] = f2bf(f1.z); a[rt].s[7] = f2bf(f1.w);
      }
      for (int ct = 0; ct < 8; ++ct) {
        BF8 b;
        b.q = *(const uint4*)(W1b + (size_t)(ct * 16 + l16) * 128 + k0);
        for (int rt = 0; rt < 2; ++rt)
          acc[rt][ct] = __builtin_amdgcn_mfma_f32_16x16x32_bf16(a[rt].v, b.v, acc[rt][ct], 0, 0, 0);
      }
    }

    for (int ct = 0; ct < 8; ++ct) {
      const int col = ct * 16 + l16;
      const float bias = b1[col];
      for (int rt = 0; rt < 2; ++rt) {
        const int r = wave * 32 + rt * 16 + quad * 4;
        for (int i = 0; i < 4; ++i)
          h_lds[r + i][col] = f2bf(logsig(acc[rt][ct][i] + bias));
      }
    }
    __syncthreads();

    f32x4 acc2[2][8];
    for (int rt = 0; rt < 2; ++rt)
      for (int ct = 0; ct < 8; ++ct) acc2[rt][ct] = vzero;

    for (int kc = 0; kc < 4; ++kc) {
      const int k0 = kc * 32 + quad * 8;
      BF8 a[2];
      for (int rt = 0; rt < 2; ++rt)
        a[rt].q = *(const uint4*)&h_lds[wave * 32 + rt * 16 + l16][k0];
      for (int ct = 0; ct < 8; ++ct) {
        BF8 b;
        b.q = *(const uint4*)(W2b + (size_t)(ct * 16 + l16) * 128 + k0);
        for (int rt = 0; rt < 2; ++rt)
          acc2[rt][ct] = __builtin_amdgcn_mfma_f32_16x16x32_bf16(a[rt].v, b.v, acc2[rt][ct], 0, 0, 0);
      }
    }

    for (int ct = 0; ct < 8; ++ct) {
      const int col = ct * 16 + l16;
      for (int rt = 0; rt < 2; ++rt) {
        const int r = row0 + wave * 32 + rt * 16 + quad * 4;
        for (int i = 0; i < 4; ++i)
          s_out[(size_t)(r + i) * 128 + col] = f2bf(logsig(acc2[rt][ct][i]));
      }
    }
  } else {
    // ---------------- mask scan ----------------
    const int n = blockIdx.x - 256;
    const int lane = tid & 63;
    if (tid == 0) cnt = 0;
    __syncthreads();

    const u32x4* row = (const u32x4*)(mask + (size_t)n * N_EDGES);
    for (int i = tid; i < N_EDGES / 4; i += 256) {
      const u32x4 v = __builtin_nontemporal_load(&row[i]);
      const uint32_t any = v[0] | v[1] | v[2] | v[3];
      const unsigned long long many = __ballot(any != 0u);
      if (many) {
#pragma unroll
        for (int k = 0; k < 4; ++k) {
          const bool p = (v[k] != 0u);
          const unsigned long long m = __ballot(p);
          if (m) {
            int base = 0;
            if (lane == 0) base = atomicAdd(&cnt, __popcll(m));
            base = __shfl(base, 0);
            if (p) {
              const int off = __popcll(m & ((1ull << lane) - 1ull));
              if (base + off < ROW_CAP) list[base + off] = i * 4 + k;
            }
          }
        }
      }
    }
    __syncthreads();

    const int c = min(cnt, ROW_CAP);
    if (tid == 0) row_cnt[n] = c;
    for (int i = tid; i < c; i += 256) {
      const int e = list[i];
      row_edges[(size_t)n * ROW_CAP + i] = e;
      const int slot = atomicAdd(&col_cnt[e], 1);
      if (slot < COL_CAP) col_nodes[(size_t)e * COL_CAP + slot] = n;
    }
  }
}

// ---------------------------------------------------------------------------
// K3: y[n,:] = sum_{e in row n} s[e,:]   (mask @ s). One block per node,
// 256 threads = 4 waves; each wave covers all 128 dims (2 dims/lane, u32
// loads) over strided edges; 4 partials combined through LDS.
// ---------------------------------------------------------------------------
__global__ __launch_bounds__(256) void pass_a(
    const u16* __restrict__ s_bf, const int* __restrict__ row_cnt,
    const int* __restrict__ row_edges, float* __restrict__ y)
{
  const int n = blockIdx.x;
  const int lane = threadIdx.x & 63;
  const int wv = threadIdx.x >> 6;
  const int d0 = lane * 2;
  __shared__ int elist[ROW_CAP];
  __shared__ float part[3][128];
  const int cnt = row_cnt[n];
  for (int i = threadIdx.x; i < cnt; i += 256)
    elist[i] = row_edges[(size_t)n * ROW_CAP + i];
  __syncthreads();
  float a0 = 0.f, a1 = 0.f;
#pragma unroll 4
  for (int i = wv; i < cnt; i += 4) {
    const uint32_t sp = *(const uint32_t*)&s_bf[(size_t)elist[i] * 128 + d0];
    a0 += bf2f((u16)(sp & 0xffffu));
    a1 += bf2f((u16)(sp >> 16));
  }
  if (wv > 0) { part[wv - 1][d0] = a0; part[wv - 1][d0 + 1] = a1; }
  __syncthreads();
  if (wv == 0) {
    a0 += part[0][d0] + part[1][d0] + part[2][d0];
    a1 += part[0][d0 + 1] + part[1][d0 + 1] + part[2][d0 + 1];
    float2 r; r.x = a0; r.y = a1;
    *(float2*)&y[n * 128 + d0] = r;
  }
}

// ---------------------------------------------------------------------------
// K4: cat[e,:] = [ (sum_{n in col e} y[n,:]) - s[e,:] | feature[e,:] ] (bf16).
// One edge per wave, 4 edges per block, 8192 blocks (high occupancy, no LDS).
// Column list preloaded one-entry-per-lane, broadcast via __shfl -> the y
// gather loads are independent (no load->load dependent chain).
// ---------------------------------------------------------------------------
__global__ __launch_bounds__(256) void pass_b(
    const float* __restrict__ y, const u16* __restrict__ s_bf,
    const float* __restrict__ feature, const int* __restrict__ col_cnt,
    const int* __restrict__ col_nodes, u16* __restrict__ cat)
{
  const int lane = threadIdx.x & 63;
  const int e = blockIdx.x * 4 + (threadIdx.x >> 6);
  const int d0 = lane * 2;
  const int cnt = min(col_cnt[e], COL_CAP);
  const int cnl = col_nodes[(size_t)e * COL_CAP + min(lane, COL_CAP - 1)];
  float a0 = 0.f, a1 = 0.f;
#pragma unroll 4
  for (int j = 0; j < cnt; ++j) {
    const int nn = __shfl(cnl, j);
    const float2 yv = *(const float2*)&y[nn * 128 + d0];
    a0 += yv.x; a1 += yv.y;
  }
  const uint32_t sp = *(const uint32_t*)&s_bf[(size_t)e * 128 + d0];
  a0 -= bf2f((u16)(sp & 0xffffu));
  a1 -= bf2f((u16)(sp >> 16));
  const uint32_t packed = (uint32_t)f2bf(a0) | ((uint32_t)f2bf(a1) << 16);
  *(uint32_t*)&cat[(size_t)e * 160 + d0] = packed;
  if (lane < 16) {
    const float2 fv = *(const float2*)&feature[e * 32 + lane * 2];
    const uint32_t pf = (uint32_t)f2bf(fv.x) | ((uint32_t)f2bf(fv.y) << 16);
    *(uint32_t*)&cat[(size_t)e * 160 + 128 + lane * 2] = pf;
  }
}

// ---------------------------------------------------------------------------
// K5: MLP_a: out = ls(ls(cat @ W1a^T + b1a) @ W2a^T), K1=160, f32 out.
// ---------------------------------------------------------------------------
__global__ __launch_bounds__(256) void mlp_a_kernel(
    const u16* __restrict__ cat, const u16* __restrict__ W1b,
    const float* __restrict__ b1, const u16* __restrict__ W2b,
    float* __restrict__ out)
{
  const int tid = threadIdx.x;
  const int wave = tid >> 6;
  const int lane = tid & 63;
  const int l16 = lane & 15;
  const int quad = lane >> 4;
  const int row0 = blockIdx.x * 128;

  __shared__ u16 h_lds[128][136];

  const f32x4 vzero = {0.f, 0.f, 0.f, 0.f};
  f32x4 acc[2][8];
  for (int rt = 0; rt < 2; ++rt)
    for (int ct = 0; ct < 8; ++ct) acc[rt][ct] = vzero;

  for (int kc = 0; kc < 5; ++kc) {
    const int k0 = kc * 32 + quad * 8;
    BF8 a[2];
    for (int rt = 0; rt < 2; ++rt)
      a[rt].q = *(const uint4*)(cat + (size_t)(row0 + wave * 32 + rt * 16 + l16) * 160 + k0);
    for (int ct = 0; ct < 8; ++ct) {
      BF8 b;
      b.q = *(const uint4*)(W1b + (size_t)(ct * 16 + l16) * 160 + k0);
      for (int rt = 0; rt < 2; ++rt)
        acc[rt][ct] = __builtin_amdgcn_mfma_f32_16x16x32_bf16(a[rt].v, b.v, acc[rt][ct], 0, 0, 0);
    }
  }

  for (int ct = 0; ct < 8; ++ct) {
    const int col = ct * 16 + l16;
    const float bias = b1[col];
    for (int rt = 0; rt < 2; ++rt) {
      const int r = wave * 32 + rt * 16 + quad * 4;
      for (int i = 0; i < 4; ++i)
        h_lds[r + i][col] = f2bf(logsig(acc[rt][ct][i] + bias));
    }
  }
  __syncthreads();

  f32x4 acc2[2][8];
  for (int rt = 0; rt < 2; ++rt)
    for (int ct = 0; ct < 8; ++ct) acc2[rt][ct] = vzero;

  for (int kc = 0; kc < 4; ++kc) {
    const int k0 = kc * 32 + quad * 8;
    BF8 a[2];
    for (int rt = 0; rt < 2; ++rt)
      a[rt].q = *(const uint4*)&h_lds[wave * 32 + rt * 16 + l16][k0];
    for (int ct = 0; ct < 8; ++ct) {
      BF8 b;
      b.q = *(const uint4*)(W2b + (size_t)(ct * 16 + l16) * 128 + k0);
      for (int rt = 0; rt < 2; ++rt)
        acc2[rt][ct] = __builtin_amdgcn_mfma_f32_16x16x32_bf16(a[rt].v, b.v, acc2[rt][ct], 0, 0, 0);
    }
  }

  for (int ct = 0; ct < 8; ++ct) {
    const int col = ct * 16 + l16;
    for (int rt = 0; rt < 2; ++rt) {
      const int r = row0 + wave * 32 + rt * 16 + quad * 4;
      for (int i = 0; i < 4; ++i)
        out[(size_t)(r + i) * 128 + col] = logsig(acc2[rt][ct][i]);
    }
  }
}

// ---------------------------------------------------------------------------
// kernel_launch
// ---------------------------------------------------------------------------
extern "C" void kernel_launch(void* const* d_in, const int* in_sizes, int n_in,
                              void* d_out, int out_size, void* d_ws, size_t ws_size,
                              hipStream_t stream)
{
  const float* state   = (const float*)d_in[0];
  const float* feature = (const float*)d_in[1];
  const float* mask    = (const float*)d_in[2];
  // d_in[3] = mask_transpose — intentionally unused (== mask.T)
  const float* W1m = (const float*)d_in[4];
  const float* b1m = (const float*)d_in[5];
  const float* W2m = (const float*)d_in[6];
  const float* W1a = (const float*)d_in[7];
  const float* b1a = (const float*)d_in[8];
  const float* W2a = (const float*)d_in[9];
  float* out = (float*)d_out;

  char* ws = (char*)d_ws;
  u16*  s_bf      = (u16*)(ws);                 //  8,388,608 B  [E,128] bf16
  u16*  cat       = (u16*)(ws + 8388608);       // 10,485,760 B  [E,160] bf16
  float* y        = (float*)(ws + 18874368);    //  1,048,576 B  [N,128] f32
  int*  row_cnt   = (int*)(ws + 19922944);      //      8,192 B
  int*  row_edges = (int*)(ws + 19931136);      //  3,145,728 B
  int*  col_cnt   = (int*)(ws + 23076864);      //    131,072 B
  int*  col_nodes = (int*)(ws + 23207936);      //  6,291,456 B
  u16*  wb        = (u16*)(ws + 29499392);      //    139,264 B  bf16 weights

  conv_weights<<<272, 256, 0, stream>>>(W1m, W2m, W1a, W2a, wb, col_cnt);
  mlp_scan<<<256 + N_NODES, 256, 0, stream>>>(state, wb, b1m, wb + 16384, s_bf,
                                              mask, row_cnt, row_edges, col_cnt, col_nodes);
  pass_a<<<N_NODES, 256, 0, stream>>>(s_bf, row_cnt, row_edges, y);
  pass_b<<<N_EDGES / 4, 256, 0, stream>>>(y, s_bf, feature, col_cnt, col_nodes, cat);
  mlp_a_kernel<<<N_EDGES / 128, 256, 0, stream>>>(cat, wb + 32768, b1a, wb + 53248, out);
}